// Round 13
// baseline (267.041 us; speedup 1.0000x reference)
//
#include <hip/hip_runtime.h>
#include <stdint.h>

// Problem constants (from reference): B=8, T=4096, D=1024, H=32.
#define D_DIM 1024
#define T_DIM 4096
#define B_DIM 8
#define M_REAL (B_DIM * (T_DIM + 1))   // 32776 output rows
#define M_MAIN 32768                    // 128 m-panels x 256 (tail 8 rows via GEMV)
#define NWG 512                         // 128 x 4 blocks

typedef short short8 __attribute__((ext_vector_type(8)));   // 8 bf16 (4 VGPRs)
typedef float floatx4 __attribute__((ext_vector_type(4)));  // 4 fp32 acc

typedef const __attribute__((address_space(1))) void* gptr_t;
typedef __attribute__((address_space(3))) void* lptr_t;

__device__ __forceinline__ ushort f2bf(float f) {
  union { float f; uint32_t u; } v; v.f = f;
  uint32_t r = v.u + 0x7FFF + ((v.u >> 16) & 1);  // RNE
  return (ushort)(r >> 16);
}
__device__ __forceinline__ float bf2f(ushort b) {
  union { uint32_t u; float f; } v; v.u = ((uint32_t)b) << 16; return v.f;
}

#define BARRIER()  asm volatile("s_barrier" ::: "memory")
#define WAIT_VM5() asm volatile("s_waitcnt vmcnt(5)" ::: "memory")
#define WAIT_VM0() asm volatile("s_waitcnt vmcnt(0)" ::: "memory")
// rule #18: sched_barrier(0) after the wait so MFMA can't hoist above it.
#define WAIT_LGKM0() do { asm volatile("s_waitcnt lgkmcnt(0)" ::: "memory"); \
                          __builtin_amdgcn_sched_barrier(0); } while (0)
#define SP1() __builtin_amdgcn_s_setprio(1)
#define SP0() __builtin_amdgcn_s_setprio(0)
// Inline-asm 16B global load (issue-order pinned via memory clobber; result
// NOT valid until a following vmcnt wait — fenced by WAIT_LGKM0's
// sched_barrier before any consuming MFMA).
#define GLOAD16(DST, P) \
  asm volatile("global_load_dwordx4 %0, %1, off" : "=v"(DST) : "v"(P) : "memory")

// ---------------------------------------------------------------------------
// Main GEMM: C[m,n] = sum_k A[m,k]*B[n,k] + bias[n].  A,B bf16 row-major.
// 256x256 tile, BK=32, 16 waves (4x4, 64x64/wave), acc 64 VGPR.
// **B bypasses LDS**: B (2MB) is L2-resident; each wave loads its 4 B frags
// directly global->regs (double-buffered register sets bA/bB), removing half
// the LDS reads (8->4/wave/K-tile) and half the staging writes — r12's
// diagnosis: LDS port is the shared bottleneck more waves can't widen.
// A stays via gload_lds double-buffer (32KB LDS).
// Counted prefetch, per iter u: issue {STAGE_A(u+1) [1 vmem] + BLOAD(u+1)
// [4 vmem]}; certify tile u with vmcnt(5) (u+1's 5 in flight); vmcnt(0) only
// at u=31. Slot (u+1)&1 restage is first-op after the trailing barrier of
// u-1 whose reads completed before it -> race-free.
// A bank swizzle (r12-proven, 0 conflicts): phys chunk kc^((row>>1)&3) via
// linear LDS dest + pre-swizzled global k ((tid&3)^((tid>>3)&3))*8; read
// offset row*64 + (lhi^((l15>>1)&3))*16. XCD swizzle m204 (nwg=512).
// ---------------------------------------------------------------------------
__global__ __launch_bounds__(1024) void gemm_w16_kernel(
    const ushort* __restrict__ A, const ushort* __restrict__ Bm,
    float* __restrict__ C, const float* __restrict__ bias)
{
  __shared__ char smem[32768];   // A slots s*16KB (s=0,1)
  const int tid  = threadIdx.x;
  const int wave = tid >> 6;
  const int lane = tid & 63;
  const int wm = wave >> 2, wn = wave & 3;   // 4x4 wave grid, 64x64 per wave
  const int l15 = lane & 15, lhi = lane >> 4;

  const int bid = blockIdx.x;
  const int wg  = (bid & 7) * 64 + (bid >> 3);
  const int n0 = (wg & 3) * 256;
  const int m0 = (wg >> 2) * 256;            // <= 32512; max row 32767 < M_REAL

  // A staging: thread stages 16B chunk tid of the 256x32 tile: row = tid>>2,
  // logical k-chunk = (tid&3) ^ ((tid>>3)&3) (bank swizzle), LDS dest linear.
  const int srow = tid >> 2;                           // 0..255
  const int ksw  = ((tid & 3) ^ ((tid >> 3) & 3)) * 8; // pre-swizzled k elems
  const ushort* ApS = A + (size_t)(m0 + srow) * D_DIM + ksw;

  // A read-side lane offsets (bytes within a 16KB tile slot).
  const int xorc = (lhi ^ ((l15 >> 1) & 3)) * 16;
  const int aoff = (wm * 64 + l15) * 64 + xorc;

  // B per-lane global base: row = n0 + wn*64 + l15, k-elems = lhi*8.
  const ushort* Bg = Bm + (size_t)(n0 + wn * 64 + l15) * D_DIM + lhi * 8;

  short8 a[4];
  short8 bA[4], bB[4];           // B frag double-buffer (register)
  floatx4 acc[4][4] = {};

#define STAGE_A(PA, S) \
  __builtin_amdgcn_global_load_lds((gptr_t)(PA), \
      (lptr_t)(smem + (S) * 16384 + wave * 1024), 16, 0, 0)

#define BLOAD(SET, U) do { \
  GLOAD16(SET[0], (Bg + (U) * 32)); \
  GLOAD16(SET[1], (Bg + 16384 + (U) * 32)); \
  GLOAD16(SET[2], (Bg + 32768 + (U) * 32)); \
  GLOAD16(SET[3], (Bg + 49152 + (U) * 32)); \
} while (0)

#define LDA_W(S) do { \
  _Pragma("unroll") \
  for (int m = 0; m < 4; ++m) \
    a[m] = *(const short8*)(smem + (S) * 16384 + aoff + m * 1024); \
} while (0)

#define MFMA_W(BSET) do { \
  _Pragma("unroll") \
  for (int m = 0; m < 4; ++m) \
    _Pragma("unroll") \
    for (int n = 0; n < 4; ++n) \
      acc[m][n] = __builtin_amdgcn_mfma_f32_16x16x32_bf16( \
          a[m], BSET[n], acc[m][n], 0, 0, 0); \
} while (0)

// One K-tile u in A-slot S0, consuming BCUR; stages u+1 and loads BNXT.
#define ITER_W(S0, BCUR, BNXT, U1, STG, VMW) do { \
  if (STG) { STAGE_A(ApS + (U1) * 32, (S0) ^ 1); BLOAD(BNXT, U1); } \
  VMW; \
  BARRIER(); \
  LDA_W(S0); \
  WAIT_LGKM0(); \
  SP1(); MFMA_W(BCUR); SP0(); \
  BARRIER(); \
} while (0)

  // Prologue: tile 0 -> slot 0 + B(0) -> bA  (5 vmem).
  STAGE_A(ApS, 0);
  BLOAD(bA, 0);

#pragma unroll 1
  for (int it = 0; it < 15; ++it) {        // u = 2*it, 2*it+1  (0..29)
    const int u = 2 * it;
    ITER_W(0, bA, bB, u + 1, 1, WAIT_VM5());
    ITER_W(1, bB, bA, u + 2, 1, WAIT_VM5());
  }
  ITER_W(0, bA, bB, 31, 1, WAIT_VM5());    // u = 30 (stages tile 31 + bB)
  ITER_W(1, bB, bA, 0, 0, WAIT_VM0());     // u = 31 (drain)

  // Epilogue. C/D layout: col = lane&15, row = (lane>>4)*4 + j.
  // Max gm = 32512 + 192 + 48 + 12 + 3 = 32767 < M_REAL -> no guard.
#pragma unroll
  for (int m = 0; m < 4; ++m)
#pragma unroll
    for (int n = 0; n < 4; ++n) {
      const int gn = n0 + wn * 64 + n * 16 + l15;
      const float bia = bias[gn];
#pragma unroll
      for (int j = 0; j < 4; ++j) {
        const int gm = m0 + wm * 64 + m * 16 + lhi * 4 + j;
        C[(size_t)gm * D_DIM + gn] = acc[m][n][j] + bia;
      }
    }
#undef STAGE_A
#undef BLOAD
#undef LDA_W
#undef MFMA_W
#undef ITER_W
}

// ---------------------------------------------------------------------------
// Tail GEMV: out[r,c] for r in [32768, 32776), all 1024 cols.
// ---------------------------------------------------------------------------
__global__ __launch_bounds__(256) void tail_gemv_kernel(
    const ushort* __restrict__ S, const ushort* __restrict__ Wf,
    const float* __restrict__ cvec, float* __restrict__ out)
{
  const int wavei = threadIdx.x >> 6, lane = threadIdx.x & 63;
  const int c = blockIdx.x * 4 + wavei;
  float acc[8] = {};
  for (int i = 0; i < 16; ++i) {
    const int k = i * 64 + lane;
    const float wv = bf2f(Wf[(size_t)c * D_DIM + k]);
#pragma unroll
    for (int r = 0; r < 8; ++r)
      acc[r] += wv * bf2f(S[(size_t)(M_MAIN + r) * D_DIM + k]);
  }
#pragma unroll
  for (int r = 0; r < 8; ++r) {
#pragma unroll
    for (int off = 32; off; off >>= 1) acc[r] += __shfl_xor(acc[r], off, 64);
  }
  if (lane == 0) {
    const float bia = cvec[c];
#pragma unroll
    for (int r = 0; r < 8; ++r)
      out[(size_t)(M_MAIN + r) * D_DIM + c] = acc[r] + bia;
  }
}

// ---------------------------------------------------------------------------
// Small GEMM for Wfused = Wo @ Wv (bf16 out): m97-style 128x128 tile, BK=64.
// ---------------------------------------------------------------------------
__global__ __launch_bounds__(256) void gemm_bt_kernel(
    const ushort* __restrict__ A, const ushort* __restrict__ Bm,
    ushort* __restrict__ Cb, int K, int N)
{
  __shared__ ushort As[128][64];   // 16 KB
  __shared__ ushort Bs[128][64];   // 16 KB
  const int tid  = threadIdx.x;
  const int wave = tid >> 6;
  const int lane = tid & 63;
  const int wm = wave >> 1, wn = wave & 1;
  const int n0 = blockIdx.x * 128, m0 = blockIdx.y * 128;
  const int l15 = lane & 15, lhi = lane >> 4;

  floatx4 acc[4][4] = {};

  const int srow = tid >> 3;
  const int sk8  = (tid & 7) * 8;
  const ushort* Ab = A  + (size_t)(m0 + srow) * K + sk8;
  const ushort* Bb = Bm + (size_t)(n0 + srow) * K + sk8;

  for (int k0 = 0; k0 < K; k0 += 64) {
#pragma unroll
    for (int q = 0; q < 4; ++q)
      __builtin_amdgcn_global_load_lds((gptr_t)(Ab + k0 + (size_t)q * 32 * K),
          (lptr_t)((char*)&As[0][0] + (q * 256 + wave * 64) * 16), 16, 0, 0);
#pragma unroll
    for (int q = 0; q < 4; ++q)
      __builtin_amdgcn_global_load_lds((gptr_t)(Bb + k0 + (size_t)q * 32 * K),
          (lptr_t)((char*)&Bs[0][0] + (q * 256 + wave * 64) * 16), 16, 0, 0);
    __syncthreads();

#pragma unroll
    for (int kk = 0; kk < 2; ++kk) {
      short8 af[4], bfrg[4];
#pragma unroll
      for (int i = 0; i < 4; ++i) {
        af[i]   = *(const short8*)(&As[wm * 64 + i * 16 + l15][kk * 32 + lhi * 8]);
        bfrg[i] = *(const short8*)(&Bs[wn * 64 + i * 16 + l15][kk * 32 + lhi * 8]);
      }
#pragma unroll
      for (int mi = 0; mi < 4; ++mi)
#pragma unroll
        for (int ni = 0; ni < 4; ++ni)
          acc[mi][ni] = __builtin_amdgcn_mfma_f32_16x16x32_bf16(
              af[mi], bfrg[ni], acc[mi][ni], 0, 0, 0);
    }
    __syncthreads();
  }

#pragma unroll
  for (int mi = 0; mi < 4; ++mi)
#pragma unroll
    for (int ni = 0; ni < 4; ++ni) {
      const int gn = n0 + wn * 64 + ni * 16 + l15;
#pragma unroll
      for (int j = 0; j < 4; ++j) {
        const int gm = m0 + wm * 64 + mi * 16 + lhi * 4 + j;
        Cb[(size_t)gm * N + gn] = f2bf(acc[mi][ni][j]);
      }
    }
}

// ---------------------------------------------------------------------------
// Depthwise temporal conv -> s_bf16.
// s[t] = sum_i w[i] x[t-32+i] (x[neg]=0), t in [0,4096].
// Ascending recurrence with batched 32-row register window + exact resync:
//   s[t] = (s[t-1] - w0*x[t-33]) / r + w31*x[t-1]
// ---------------------------------------------------------------------------
#define CTCH 128
__global__ __launch_bounds__(256) void conv_kernel(
    const float* __restrict__ x, const float* __restrict__ dw,
    ushort* __restrict__ S)
{
  const int b   = blockIdx.y;
  const int col = blockIdx.z * 256 + threadIdx.x;   // 0..1023
  const int t0  = blockIdx.x * CTCH;

  float w[32];
#pragma unroll
  for (int i = 0; i < 32; ++i) w[i] = dw[i];
  const float rinv = w[0] / w[1];                    // 1/r
  const float w31  = w[31];
  const float c0   = -w[0] * rinv;                   // -(w0/r)

  const float* xb = x + (size_t)b * T_DIM * D_DIM + col;
  ushort*      Sb = S + (size_t)b * (T_DIM + 1) * D_DIM + col;

  float prev[32], cur[32];
  float s;
  if (blockIdx.x == 0) {
#pragma unroll
    for (int i = 0; i < 32; ++i) prev[i] = 0.f;
    s = 0.f;
    Sb[0] = f2bf(0.f);                               // row t=0
  } else {
#pragma unroll
    for (int i = 0; i < 32; ++i) prev[i] = xb[(size_t)(t0 - 32 + i) * D_DIM];
    s = 0.f;
#pragma unroll
    for (int i = 0; i < 32; ++i) s = __builtin_fmaf(w[i], prev[i], s);
  }

#pragma unroll 1
  for (int g = 0; g < 4; g += 2) {
#pragma unroll
    for (int i = 0; i < 32; ++i) cur[i] = xb[(size_t)(t0 + g * 32 + i) * D_DIM];
#pragma unroll
    for (int j = 0; j < 32; ++j) {
      s = __builtin_fmaf(s, rinv, __builtin_fmaf(prev[j], c0, w31 * cur[j]));
      Sb[(size_t)(t0 + g * 32 + 1 + j) * D_DIM] = f2bf(s);
    }
    s = 0.f;                                         // exact resync from cur
#pragma unroll
    for (int i = 0; i < 32; ++i) s = __builtin_fmaf(w[i], cur[i], s);
#pragma unroll
    for (int i = 0; i < 32; ++i) prev[i] = xb[(size_t)(t0 + (g + 1) * 32 + i) * D_DIM];
#pragma unroll
    for (int j = 0; j < 32; ++j) {
      s = __builtin_fmaf(s, rinv, __builtin_fmaf(cur[j], c0, w31 * prev[j]));
      Sb[(size_t)(t0 + (g + 1) * 32 + 1 + j) * D_DIM] = f2bf(s);
    }
    s = 0.f;
#pragma unroll
    for (int i = 0; i < 32; ++i) s = __builtin_fmaf(w[i], prev[i], s);
  }
}

// Wo fp32 -> bf16 straight copy.
__global__ void convert_wo_kernel(const float* __restrict__ Wo, ushort* __restrict__ WoB) {
  const int i = blockIdx.x * 256 + threadIdx.x;      // float4 index
  const float4 v = ((const float4*)Wo)[i];
  ushort4 o = make_ushort4(f2bf(v.x), f2bf(v.y), f2bf(v.z), f2bf(v.w));
  *(ushort4*)(WoB + (size_t)i * 4) = o;
}

// Wv fp32 -> WvT bf16 (transpose via LDS 32x32 tile).
__global__ void transpose_wv_kernel(const float* __restrict__ Wv, ushort* __restrict__ WvT) {
  __shared__ float tile[32][33];
  const int tx = threadIdx.x;   // 0..31
  const int ty = threadIdx.y;   // 0..7
  const int c0 = blockIdx.x * 32;
  const int r0 = blockIdx.y * 32;
#pragma unroll
  for (int j = 0; j < 4; ++j)
    tile[ty + j * 8][tx] = Wv[(size_t)(r0 + ty + j * 8) * D_DIM + c0 + tx];
  __syncthreads();
#pragma unroll
  for (int j = 0; j < 4; ++j)
    WvT[(size_t)(c0 + ty + j * 8) * D_DIM + r0 + tx] = f2bf(tile[tx][ty + j * 8]);
}

// cvec[j] = sum(dw) * dot(Wo[j,:], bv) + bo[j].  One wave per j.
__global__ void bias_kernel(const float* __restrict__ Wo, const float* __restrict__ bv,
                            const float* __restrict__ bo, const float* __restrict__ dw,
                            float* __restrict__ cvec) {
  const int j    = blockIdx.x * 4 + (threadIdx.x >> 6);
  const int lane = threadIdx.x & 63;
  float sumw = 0.f;
#pragma unroll
  for (int i = 0; i < 32; ++i) sumw += dw[i];
  float s = 0.f;
  for (int k = lane; k < D_DIM; k += 64) s += Wo[(size_t)j * D_DIM + k] * bv[k];
#pragma unroll
  for (int off = 32; off; off >>= 1) s += __shfl_xor(s, off, 64);
  if (lane == 0) cvec[j] = sumw * s + bo[j];
}

// ---------------------------------------------------------------------------
extern "C" void kernel_launch(void* const* d_in, const int* in_sizes, int n_in,
                              void* d_out, int out_size, void* d_ws, size_t ws_size,
                              hipStream_t stream) {
  const float* x  = (const float*)d_in[0];
  const float* Wv = (const float*)d_in[1];
  const float* bv = (const float*)d_in[2];
  const float* Wo = (const float*)d_in[3];
  const float* bo = (const float*)d_in[4];
  const float* dw = (const float*)d_in[5];
  float* out = (float*)d_out;

  // Workspace layout (~73.4 MB total).
  char* ws = (char*)d_ws;
  ushort* S      = (ushort*)ws;                                  // M_REAL*1024 bf16
  ushort* WoB    = (ushort*)(ws + (size_t)M_REAL * D_DIM * 2);   // 1024^2 bf16
  ushort* WvT    = WoB + (size_t)D_DIM * D_DIM;                  // 1024^2 bf16
  ushort* Wfused = WvT + (size_t)D_DIM * D_DIM;                  // 1024^2 bf16
  float*  cvec   = (float*)(Wfused + (size_t)D_DIM * D_DIM);     // 1024 fp32

  // 1) Weight prep (all tiny).
  convert_wo_kernel<<<dim3(D_DIM * D_DIM / 1024), dim3(256), 0, stream>>>(Wo, WoB);
  transpose_wv_kernel<<<dim3(32, 32), dim3(32, 8), 0, stream>>>(Wv, WvT);
  bias_kernel<<<dim3(256), dim3(256), 0, stream>>>(Wo, bv, bo, dw, cvec);

  // 2) Wfused[j,k] = sum_p Wo[j,p] * Wv[p,k]  (row-major bf16).
  gemm_bt_kernel<<<dim3(8, 8), dim3(256), 0, stream>>>(
      WoB, WvT, Wfused, D_DIM, D_DIM);

  // 3) Temporal conv -> s bf16 (batched-window recurrence).
  conv_kernel<<<dim3(T_DIM / CTCH, B_DIM, 4), dim3(256), 0, stream>>>(x, dw, S);

  // 4) out = s @ Wfused^T + cvec  (256^2, 16-wave BK32, A via 32KB LDS 2-buf,
  //    B direct from L2 into regs, counted vmcnt(5), XCD-swizzled) + tail.
  gemm_w16_kernel<<<dim3(NWG), dim3(1024), 0, stream>>>(S, Wfused, out, cvec);
  tail_gemv_kernel<<<dim3(256), dim3(256), 0, stream>>>(S, Wfused, cvec, out);
}

// Round 14
// 156.972 us; speedup vs baseline: 1.7012x; 1.7012x over previous
//
#include <hip/hip_runtime.h>
#include <stdint.h>

// Problem constants (from reference): B=8, T=4096, D=1024, H=32.
#define D_DIM 1024
#define T_DIM 4096
#define B_DIM 8
#define M_REAL (B_DIM * (T_DIM + 1))   // 32776 output rows
#define M_MAIN 32768                    // 128 m-panels x 256 (tail 8 rows via GEMV)
#define NWG 512                         // 128 x 4 blocks; 2 blocks/CU resident

typedef short short8 __attribute__((ext_vector_type(8)));   // 8 bf16 (4 VGPRs)
typedef float floatx4 __attribute__((ext_vector_type(4)));  // 4 fp32 acc

typedef const __attribute__((address_space(1))) void* gptr_t;
typedef __attribute__((address_space(3))) void* lptr_t;

__device__ __forceinline__ ushort f2bf(float f) {
  union { float f; uint32_t u; } v; v.f = f;
  uint32_t r = v.u + 0x7FFF + ((v.u >> 16) & 1);  // RNE
  return (ushort)(r >> 16);
}
__device__ __forceinline__ float bf2f(ushort b) {
  union { uint32_t u; float f; } v; v.u = ((uint32_t)b) << 16; return v.f;
}

#define BARRIER()  asm volatile("s_barrier" ::: "memory")
#define WAIT_VM2() asm volatile("s_waitcnt vmcnt(2)" ::: "memory")
#define WAIT_VM0() asm volatile("s_waitcnt vmcnt(0)" ::: "memory")
// rule #18: sched_barrier(0) after the wait so MFMA can't hoist above it.
#define WAIT_LGKM0() do { asm volatile("s_waitcnt lgkmcnt(0)" ::: "memory"); \
                          __builtin_amdgcn_sched_barrier(0); } while (0)
#define SP1() __builtin_amdgcn_s_setprio(1)
#define SP0() __builtin_amdgcn_s_setprio(0)

// ---------------------------------------------------------------------------
// Main GEMM (r12-proven best): C[m,n] = sum_k A[m,k]*B[n,k] + bias[n].
// 256x256 tile, BK=32, 16 waves (4x4, 64x64 per wave), VGPR 64 + acc 64 AGPR
// -> 128 unified regs/wave -> 4 waves/SIMD. 2-buffer 64KB LDS -> 2 blocks/CU.
// Counted prefetch: stage tile u+1 at top of iter u into slot (u+1)&1;
// certify tile u with vmcnt(2); vmcnt(0) only at u=31.
// Bank swizzle (0 conflicts): phys chunk = kc ^ ((row>>1)&3) via linear LDS
// dest + pre-swizzled global k ((tid&3)^((tid>>3)&3))*8; read offset
// row*64 + (lhi^((l15>>1)&3))*16. XCD swizzle m204 (nwg=512: q=64, r=0).
// ---------------------------------------------------------------------------
__global__ __launch_bounds__(1024) void gemm_w16_kernel(
    const ushort* __restrict__ A, const ushort* __restrict__ Bm,
    float* __restrict__ C, const float* __restrict__ bias)
{
  __shared__ char smem[65536];   // A slots s*16KB (s=0,1); B at 32768 + s*16KB
  const int tid  = threadIdx.x;
  const int wave = tid >> 6;
  const int lane = tid & 63;
  const int wm = wave >> 2, wn = wave & 3;   // 4x4 wave grid, 64x64 per wave
  const int l15 = lane & 15, lhi = lane >> 4;

  const int bid = blockIdx.x;
  const int wg  = (bid & 7) * 64 + (bid >> 3);
  const int n0 = (wg & 3) * 256;
  const int m0 = (wg >> 2) * 256;            // <= 32512; max row 32767 < M_REAL

  // Staging: thread stages 16B chunk p = tid of the 256x32 tile: row = tid>>2,
  // logical k-chunk = (tid&3) ^ ((tid>>3)&3) (bank swizzle), LDS dest linear.
  const int srow = tid >> 2;                           // 0..255
  const int ksw  = ((tid & 3) ^ ((tid >> 3) & 3)) * 8; // pre-swizzled k elems
  const ushort* Aq = A  + (size_t)(m0 + srow) * D_DIM + ksw;
  const ushort* Bq = Bm + (size_t)(n0 + srow) * D_DIM + ksw;

  // Read-side lane offsets (bytes within a 16KB tile slot).
  const int xorc = (lhi ^ ((l15 >> 1) & 3)) * 16;
  const int aoff = (wm * 64 + l15) * 64 + xorc;
  const int boff = (wn * 64 + l15) * 64 + xorc;

  short8 a[4], b[4];
  floatx4 acc[4][4] = {};

#define STAGE_W(PA, PB, S) do { \
  __builtin_amdgcn_global_load_lds((gptr_t)(PA), \
      (lptr_t)(smem + (S) * 16384 + wave * 1024), 16, 0, 0); \
  __builtin_amdgcn_global_load_lds((gptr_t)(PB), \
      (lptr_t)(smem + 32768 + (S) * 16384 + wave * 1024), 16, 0, 0); \
} while (0)

#define LDAB_W(S) do { \
  _Pragma("unroll") \
  for (int m = 0; m < 4; ++m) \
    a[m] = *(const short8*)(smem + (S) * 16384 + aoff + m * 1024); \
  _Pragma("unroll") \
  for (int n = 0; n < 4; ++n) \
    b[n] = *(const short8*)(smem + 32768 + (S) * 16384 + boff + n * 1024); \
} while (0)

#define MFMA_W() do { \
  _Pragma("unroll") \
  for (int m = 0; m < 4; ++m) \
    _Pragma("unroll") \
    for (int n = 0; n < 4; ++n) \
      acc[m][n] = __builtin_amdgcn_mfma_f32_16x16x32_bf16( \
          a[m], b[n], acc[m][n], 0, 0, 0); \
} while (0)

// One K-tile in slot S0. STG: stage tile u+1 into slot S0^1. VMW: counted wait.
#define ITER_W(S0, STG, VMW) do { \
  if (STG) { STAGE_W(ApS, BpS, (S0) ^ 1); ApS += 32; BpS += 32; } \
  VMW; \
  BARRIER(); \
  LDAB_W(S0); \
  WAIT_LGKM0(); \
  SP1(); MFMA_W(); SP0(); \
  BARRIER(); \
} while (0)

  // Prologue: tile 0 -> slot 0 (2 loads/thread).
  STAGE_W(Aq, Bq, 0);
  const ushort* ApS = Aq + 32;   // next staged tile = 1
  const ushort* BpS = Bq + 32;

#pragma unroll 1
  for (int it = 0; it < 15; ++it) {        // u = 2*it, 2*it+1  (0..29)
    ITER_W(0, 1, WAIT_VM2());
    ITER_W(1, 1, WAIT_VM2());
  }
  ITER_W(0, 1, WAIT_VM2());                // u = 30 (stages tile 31)
  ITER_W(1, 0, WAIT_VM0());                // u = 31

  // Epilogue. C/D layout: col = lane&15, row = (lane>>4)*4 + j.
  // Max gm = 32512 + 192 + 48 + 12 + 3 = 32767 < M_REAL -> no guard.
#pragma unroll
  for (int m = 0; m < 4; ++m)
#pragma unroll
    for (int n = 0; n < 4; ++n) {
      const int gn = n0 + wn * 64 + n * 16 + l15;
      const float bia = bias[gn];
#pragma unroll
      for (int j = 0; j < 4; ++j) {
        const int gm = m0 + wm * 64 + m * 16 + lhi * 4 + j;
        C[(size_t)gm * D_DIM + gn] = acc[m][n][j] + bia;
      }
    }
#undef STAGE_W
#undef LDAB_W
#undef MFMA_W
#undef ITER_W
}

// ---------------------------------------------------------------------------
// Tail GEMV: out[r,c] for r in [32768, 32776), all 1024 cols.
// ---------------------------------------------------------------------------
__global__ __launch_bounds__(256) void tail_gemv_kernel(
    const ushort* __restrict__ S, const ushort* __restrict__ Wf,
    const float* __restrict__ cvec, float* __restrict__ out)
{
  const int wavei = threadIdx.x >> 6, lane = threadIdx.x & 63;
  const int c = blockIdx.x * 4 + wavei;
  float acc[8] = {};
  for (int i = 0; i < 16; ++i) {
    const int k = i * 64 + lane;
    const float wv = bf2f(Wf[(size_t)c * D_DIM + k]);
#pragma unroll
    for (int r = 0; r < 8; ++r)
      acc[r] += wv * bf2f(S[(size_t)(M_MAIN + r) * D_DIM + k]);
  }
#pragma unroll
  for (int r = 0; r < 8; ++r) {
#pragma unroll
    for (int off = 32; off; off >>= 1) acc[r] += __shfl_xor(acc[r], off, 64);
  }
  if (lane == 0) {
    const float bia = cvec[c];
#pragma unroll
    for (int r = 0; r < 8; ++r)
      out[(size_t)(M_MAIN + r) * D_DIM + c] = acc[r] + bia;
  }
}

// ---------------------------------------------------------------------------
// Small GEMM for Wfused = Wo @ Wv (bf16 out): m97-style 128x128 tile, BK=64.
// ---------------------------------------------------------------------------
__global__ __launch_bounds__(256) void gemm_bt_kernel(
    const ushort* __restrict__ A, const ushort* __restrict__ Bm,
    ushort* __restrict__ Cb, int K, int N)
{
  __shared__ ushort As[128][64];   // 16 KB
  __shared__ ushort Bs[128][64];   // 16 KB
  const int tid  = threadIdx.x;
  const int wave = tid >> 6;
  const int lane = tid & 63;
  const int wm = wave >> 1, wn = wave & 1;
  const int n0 = blockIdx.x * 128, m0 = blockIdx.y * 128;
  const int l15 = lane & 15, lhi = lane >> 4;

  floatx4 acc[4][4] = {};

  const int srow = tid >> 3;
  const int sk8  = (tid & 7) * 8;
  const ushort* Ab = A  + (size_t)(m0 + srow) * K + sk8;
  const ushort* Bb = Bm + (size_t)(n0 + srow) * K + sk8;

  for (int k0 = 0; k0 < K; k0 += 64) {
#pragma unroll
    for (int q = 0; q < 4; ++q)
      __builtin_amdgcn_global_load_lds((gptr_t)(Ab + k0 + (size_t)q * 32 * K),
          (lptr_t)((char*)&As[0][0] + (q * 256 + wave * 64) * 16), 16, 0, 0);
#pragma unroll
    for (int q = 0; q < 4; ++q)
      __builtin_amdgcn_global_load_lds((gptr_t)(Bb + k0 + (size_t)q * 32 * K),
          (lptr_t)((char*)&Bs[0][0] + (q * 256 + wave * 64) * 16), 16, 0, 0);
    __syncthreads();

#pragma unroll
    for (int kk = 0; kk < 2; ++kk) {
      short8 af[4], bfrg[4];
#pragma unroll
      for (int i = 0; i < 4; ++i) {
        af[i]   = *(const short8*)(&As[wm * 64 + i * 16 + l15][kk * 32 + lhi * 8]);
        bfrg[i] = *(const short8*)(&Bs[wn * 64 + i * 16 + l15][kk * 32 + lhi * 8]);
      }
#pragma unroll
      for (int mi = 0; mi < 4; ++mi)
#pragma unroll
        for (int ni = 0; ni < 4; ++ni)
          acc[mi][ni] = __builtin_amdgcn_mfma_f32_16x16x32_bf16(
              af[mi], bfrg[ni], acc[mi][ni], 0, 0, 0);
    }
    __syncthreads();
  }

#pragma unroll
  for (int mi = 0; mi < 4; ++mi)
#pragma unroll
    for (int ni = 0; ni < 4; ++ni) {
      const int gn = n0 + wn * 64 + ni * 16 + l15;
#pragma unroll
      for (int j = 0; j < 4; ++j) {
        const int gm = m0 + wm * 64 + mi * 16 + lhi * 4 + j;
        Cb[(size_t)gm * N + gn] = f2bf(acc[mi][ni][j]);
      }
    }
}

// ---------------------------------------------------------------------------
// Depthwise temporal conv -> s_bf16.
// s[t] = sum_i w[i] x[t-32+i] (x[neg]=0), t in [0,4096].
// Ascending recurrence with batched 32-row register window + exact resync:
//   s[t] = (s[t-1] - w0*x[t-33]) / r + w31*x[t-1]
// CTCH=256: reads (32+256)/256 = 1.125 rows/output (was 1.25 at 128).
// Grid (16, 8, 4) = 512 blocks (2/CU, 8 waves/CU).
// ---------------------------------------------------------------------------
#define CTCH 256
__global__ __launch_bounds__(256) void conv_kernel(
    const float* __restrict__ x, const float* __restrict__ dw,
    ushort* __restrict__ S)
{
  const int b   = blockIdx.y;
  const int col = blockIdx.z * 256 + threadIdx.x;   // 0..1023
  const int t0  = blockIdx.x * CTCH;

  float w[32];
#pragma unroll
  for (int i = 0; i < 32; ++i) w[i] = dw[i];
  const float rinv = w[0] / w[1];                    // 1/r
  const float w31  = w[31];
  const float c0   = -w[0] * rinv;                   // -(w0/r)

  const float* xb = x + (size_t)b * T_DIM * D_DIM + col;
  ushort*      Sb = S + (size_t)b * (T_DIM + 1) * D_DIM + col;

  float prev[32], cur[32];
  float s;
  if (blockIdx.x == 0) {
#pragma unroll
    for (int i = 0; i < 32; ++i) prev[i] = 0.f;
    s = 0.f;
    Sb[0] = f2bf(0.f);                               // row t=0
  } else {
#pragma unroll
    for (int i = 0; i < 32; ++i) prev[i] = xb[(size_t)(t0 - 32 + i) * D_DIM];
    s = 0.f;
#pragma unroll
    for (int i = 0; i < 32; ++i) s = __builtin_fmaf(w[i], prev[i], s);
  }

#pragma unroll 1
  for (int g = 0; g < 8; g += 2) {
#pragma unroll
    for (int i = 0; i < 32; ++i) cur[i] = xb[(size_t)(t0 + g * 32 + i) * D_DIM];
#pragma unroll
    for (int j = 0; j < 32; ++j) {
      s = __builtin_fmaf(s, rinv, __builtin_fmaf(prev[j], c0, w31 * cur[j]));
      Sb[(size_t)(t0 + g * 32 + 1 + j) * D_DIM] = f2bf(s);
    }
    s = 0.f;                                         // exact resync from cur
#pragma unroll
    for (int i = 0; i < 32; ++i) s = __builtin_fmaf(w[i], cur[i], s);
#pragma unroll
    for (int i = 0; i < 32; ++i) prev[i] = xb[(size_t)(t0 + (g + 1) * 32 + i) * D_DIM];
#pragma unroll
    for (int j = 0; j < 32; ++j) {
      s = __builtin_fmaf(s, rinv, __builtin_fmaf(cur[j], c0, w31 * prev[j]));
      Sb[(size_t)(t0 + (g + 1) * 32 + 1 + j) * D_DIM] = f2bf(s);
    }
    s = 0.f;
#pragma unroll
    for (int i = 0; i < 32; ++i) s = __builtin_fmaf(w[i], prev[i], s);
  }
}

// ---------------------------------------------------------------------------
// Merged weight prep: blocks [0,1024): Wo->bf16; [1024,2048): Wv->WvT bf16;
// [2048,2304): cvec[j] = sum(dw)*dot(Wo[j,:],bv) + bo[j].
// Branch is uniform per block (on blockIdx) -> __syncthreads safe.
// ---------------------------------------------------------------------------
__global__ __launch_bounds__(256) void prep_kernel(
    const float* __restrict__ Wo, const float* __restrict__ Wv,
    const float* __restrict__ bv, const float* __restrict__ bo,
    const float* __restrict__ dw,
    ushort* __restrict__ WoB, ushort* __restrict__ WvT,
    float* __restrict__ cvec)
{
  __shared__ float tile[32][33];
  const int bid = blockIdx.x;
  const int tid = threadIdx.x;

  if (bid < 1024) {            // Wo fp32 -> bf16 straight copy (float4)
    const int i = bid * 256 + tid;
    const float4 v = ((const float4*)Wo)[i];
    ushort4 o = make_ushort4(f2bf(v.x), f2bf(v.y), f2bf(v.z), f2bf(v.w));
    *(ushort4*)(WoB + (size_t)i * 4) = o;
  } else if (bid < 2048) {     // Wv transpose -> WvT bf16 (32x32 LDS tile)
    const int b2 = bid - 1024;
    const int c0 = (b2 & 31) * 32, r0 = (b2 >> 5) * 32;
    const int tx = tid & 31, ty = tid >> 5;    // 32 x 8
#pragma unroll
    for (int j = 0; j < 4; ++j)
      tile[ty + j * 8][tx] = Wv[(size_t)(r0 + ty + j * 8) * D_DIM + c0 + tx];
    __syncthreads();
#pragma unroll
    for (int j = 0; j < 4; ++j)
      WvT[(size_t)(c0 + ty + j * 8) * D_DIM + r0 + tx] = f2bf(tile[tx][ty + j * 8]);
  } else {                     // bias vector, one wave per j
    const int j    = (bid - 2048) * 4 + (tid >> 6);
    const int lane = tid & 63;
    float sumw = 0.f;
#pragma unroll
    for (int i = 0; i < 32; ++i) sumw += dw[i];
    float s = 0.f;
    for (int k = lane; k < D_DIM; k += 64) s += Wo[(size_t)j * D_DIM + k] * bv[k];
#pragma unroll
    for (int off = 32; off; off >>= 1) s += __shfl_xor(s, off, 64);
    if (lane == 0) cvec[j] = sumw * s + bo[j];
  }
}

// ---------------------------------------------------------------------------
extern "C" void kernel_launch(void* const* d_in, const int* in_sizes, int n_in,
                              void* d_out, int out_size, void* d_ws, size_t ws_size,
                              hipStream_t stream) {
  const float* x  = (const float*)d_in[0];
  const float* Wv = (const float*)d_in[1];
  const float* bv = (const float*)d_in[2];
  const float* Wo = (const float*)d_in[3];
  const float* bo = (const float*)d_in[4];
  const float* dw = (const float*)d_in[5];
  float* out = (float*)d_out;

  // Workspace layout (~73.4 MB total).
  char* ws = (char*)d_ws;
  ushort* S      = (ushort*)ws;                                  // M_REAL*1024 bf16
  ushort* WoB    = (ushort*)(ws + (size_t)M_REAL * D_DIM * 2);   // 1024^2 bf16
  ushort* WvT    = WoB + (size_t)D_DIM * D_DIM;                  // 1024^2 bf16
  ushort* Wfused = WvT + (size_t)D_DIM * D_DIM;                  // 1024^2 bf16
  float*  cvec   = (float*)(Wfused + (size_t)D_DIM * D_DIM);     // 1024 fp32

  // 1) Merged weight prep.
  prep_kernel<<<dim3(2304), dim3(256), 0, stream>>>(
      Wo, Wv, bv, bo, dw, WoB, WvT, cvec);

  // 2) Wfused[j,k] = sum_p Wo[j,p] * Wv[p,k]  (row-major bf16).
  gemm_bt_kernel<<<dim3(8, 8), dim3(256), 0, stream>>>(
      WoB, WvT, Wfused, D_DIM, D_DIM);

  // 3) Temporal conv -> s bf16 (batched-window recurrence, CTCH=256).
  conv_kernel<<<dim3(T_DIM / CTCH, B_DIM, 4), dim3(256), 0, stream>>>(x, dw, S);

  // 4) out = s @ Wfused^T + cvec  (256^2, 16-wave BK32, 2-buf 64KB ->
  //    2 blocks/CU, counted vmcnt(2), XCD-swizzled) + 8-row GEMV tail.
  gemm_w16_kernel<<<dim3(NWG), dim3(1024), 0, stream>>>(S, Wfused, out, cvec);
  tail_gemv_kernel<<<dim3(256), dim3(256), 0, stream>>>(S, Wfused, cvec, out);
}